// Round 6
// baseline (317.133 us; speedup 1.0000x reference)
//
#include <hip/hip_runtime.h>
#include <hip/hip_bf16.h>
#include <cstdint>

#define TOKENS 8192
#define IN_F   4096
#define OUT_F  4096

#define BM 256
#define BN 256
#define BK 64
#define NT (IN_F / BK)   // 64 K-tiles
#define THREADS 512

typedef __attribute__((ext_vector_type(8))) short bf16x8;
typedef __attribute__((ext_vector_type(4))) float f32x4;

#define GLOBAL_AS __attribute__((address_space(1)))
#define LDS_AS    __attribute__((address_space(3)))

#define BARRIER() do { __builtin_amdgcn_s_barrier(); asm volatile("" ::: "memory"); } while (0)
#define VMCNT(n)  do { asm volatile("s_waitcnt vmcnt(" #n ")" ::: "memory"); } while (0)

__device__ __forceinline__ unsigned short f2bf(float f) {
  union { float f; unsigned int u; } v;
  v.f = f;
  unsigned int r = 0x7FFFu + ((v.u >> 16) & 1u);
  return (unsigned short)((v.u + r) >> 16);
}

__device__ __forceinline__ float softplus_f(float x) {
  return log1pf(expf(x));
}

// ---------------- fused prep kernel ----------------

#define NW4 ((long long)OUT_F * IN_F / 4)
#define NX4 ((long long)TOKENS * IN_F / 4)
#define NB4 (OUT_F / 4)

__global__ void prep_kernel(const float* __restrict__ x,
                            const float* __restrict__ wmu,
                            const float* __restrict__ wrho,
                            const float* __restrict__ weps,
                            const float* __restrict__ bmu,
                            const float* __restrict__ brho,
                            const float* __restrict__ beps,
                            unsigned short* __restrict__ xb,
                            unsigned short* __restrict__ wb,
                            float* __restrict__ bias) {
  long long i = (long long)blockIdx.x * blockDim.x + threadIdx.x;
  long long stride = (long long)gridDim.x * blockDim.x;
  const long long total = NW4 + NX4 + NB4;
  for (; i < total; i += stride) {
    if (i < NW4) {
      float4 m = reinterpret_cast<const float4*>(wmu)[i];
      float4 r = reinterpret_cast<const float4*>(wrho)[i];
      float4 e = reinterpret_cast<const float4*>(weps)[i];
      ushort4 o;
      o.x = f2bf(fmaf(softplus_f(r.x), e.x, m.x));
      o.y = f2bf(fmaf(softplus_f(r.y), e.y, m.y));
      o.z = f2bf(fmaf(softplus_f(r.z), e.z, m.z));
      o.w = f2bf(fmaf(softplus_f(r.w), e.w, m.w));
      reinterpret_cast<ushort4*>(wb)[i] = o;
    } else if (i < NW4 + NX4) {
      long long j = i - NW4;
      float4 m = reinterpret_cast<const float4*>(x)[j];
      ushort4 o;
      o.x = f2bf(m.x); o.y = f2bf(m.y); o.z = f2bf(m.z); o.w = f2bf(m.w);
      reinterpret_cast<ushort4*>(xb)[j] = o;
    } else {
      long long j = i - NW4 - NX4;
      float4 m = reinterpret_cast<const float4*>(bmu)[j];
      float4 r = reinterpret_cast<const float4*>(brho)[j];
      float4 e = reinterpret_cast<const float4*>(beps)[j];
      float4 o;
      o.x = fmaf(softplus_f(r.x), e.x, m.x);
      o.y = fmaf(softplus_f(r.y), e.y, m.y);
      o.z = fmaf(softplus_f(r.z), e.z, m.z);
      o.w = fmaf(softplus_f(r.w), e.w, m.w);
      reinterpret_cast<float4*>(bias)[j] = o;
    }
  }
}

// ---------------- GEMM: 256x256, 4 phases/tile, register-pipelined frags ----------------
// LDS 160 KiB: A ring 3 x 32 KiB + B ring 2 x 32 KiB. 8 waves (2M x 4N),
// per-wave out 128x64. Fragment reads run ONE PHASE AHEAD of the MFMA that
// consumes them (avX/avY ping-pong) so LDS drain overlaps the MFMA cluster.
// TILE-BOUNDARY PUBLISH (race fix vs r5): per-wave VMCNT(8) + BARRIER at the
// END of ph2 makes tile t+1's cooperative staging globally visible; the
// next-tile preloads (B(t+1), A(t+1).q0) run in ph3 strictly AFTER it.
// Staging of tile t+2 spread over ph0..ph2 (issue-to-wait >= 5 phases).
// LDS swizzle: chunk ^= (row & 7) via pre-swizzled global source (linear
// global_load_lds dest) + matching XOR on ds_read (rule 21 involution).

__global__ __launch_bounds__(THREADS, 2) void gemm_bt_kernel(
    const unsigned short* __restrict__ A,   // [TOKENS][IN_F] bf16
    const unsigned short* __restrict__ B,   // [OUT_F][IN_F] bf16
    const float* __restrict__ bias,         // [OUT_F]
    float* __restrict__ C)                  // [TOKENS][OUT_F]
{
  __shared__ unsigned short lds[5 * 16384]; // 160 KiB

  const int tid  = threadIdx.x;
  const int lane = tid & 63;
  const int wave = tid >> 6;   // 0..7
  const int wm   = wave >> 2;  // 0..1
  const int wn   = wave & 3;   // 0..3

  // XCD-aware bijective block swizzle (512 = 8 XCD chunks x 64)
  const int bid = blockIdx.x;
  const int wg  = (bid & 7) * 64 + (bid >> 3);
  const int ch  = wg >> 6;
  const int idx = wg & 63;
  const int bm  = (ch >> 1) * 8 + (idx >> 3);  // 0..31
  const int bn  = (ch & 1) * 8 + (idx & 7);    // 0..15

  const int lane15 = lane & 15;
  const int cgrp   = lane >> 4;                // 0..3
  const int rdoff0 = lane15 * 64 + ((cgrp ^ (lane & 7)) * 8);
  const int rdoff1 = lane15 * 64 + (((4 + cgrp) ^ (lane & 7)) * 8);

  // staging: per-lane pre-swizzled global source
  const int srow = lane >> 3;                  // 0..7
  const int scol = ((lane & 7) ^ srow) * 8;    // swizzled 16B chunk -> elems
  const unsigned short* Asrc = A + (size_t)(bm * BM + wave * 16 + srow) * IN_F + scol;
  const unsigned short* Bsrc = B + (size_t)(bn * BN + wave * 16 + srow) * IN_F + scol;

  f32x4 acc[8][4] = {};

  auto stA = [&](int slot, int half, int t) {
    unsigned short* dst = &lds[slot * 16384 + half * 8192 + wave * 1024];
    const unsigned short* g = Asrc + (size_t)(half * 128) * IN_F + t * BK;
    __builtin_amdgcn_global_load_lds((const GLOBAL_AS void*)g,
                                     (LDS_AS void*)dst, 16, 0, 0);
    __builtin_amdgcn_global_load_lds((const GLOBAL_AS void*)(g + (size_t)8 * IN_F),
                                     (LDS_AS void*)(dst + 512), 16, 0, 0);
  };
  auto stB = [&](int slot, int half, int t) {
    unsigned short* dst = &lds[49152 + slot * 16384 + half * 8192 + wave * 1024];
    const unsigned short* g = Bsrc + (size_t)(half * 128) * IN_F + t * BK;
    __builtin_amdgcn_global_load_lds((const GLOBAL_AS void*)g,
                                     (LDS_AS void*)dst, 16, 0, 0);
    __builtin_amdgcn_global_load_lds((const GLOBAL_AS void*)(g + (size_t)8 * IN_F),
                                     (LDS_AS void*)(dst + 512), 16, 0, 0);
  };

  auto rdA = [&](const unsigned short* Ar, int q, bf16x8 (&av)[2][2]) {
#pragma unroll
    for (int f = 0; f < 2; ++f) {
      const unsigned short* p = Ar + (wm * 128 + q * 32 + f * 16) * 64;
      av[f][0] = *reinterpret_cast<const bf16x8*>(p + rdoff0);
      av[f][1] = *reinterpret_cast<const bf16x8*>(p + rdoff1);
    }
  };
  auto rdB = [&](const unsigned short* Br, bf16x8 (&bv)[4][2]) {
#pragma unroll
    for (int n = 0; n < 4; ++n) {
      const unsigned short* p = Br + (wn * 64 + n * 16) * 64;
      bv[n][0] = *reinterpret_cast<const bf16x8*>(p + rdoff0);
      bv[n][1] = *reinterpret_cast<const bf16x8*>(p + rdoff1);
    }
  };
  auto mfma16 = [&](bf16x8 (&av)[2][2], bf16x8 (&bv)[4][2], f32x4* r0, f32x4* r1) {
    __builtin_amdgcn_s_setprio(1);
#pragma unroll
    for (int kk = 0; kk < 2; ++kk) {
#pragma unroll
      for (int n = 0; n < 4; ++n) {
        r0[n] = __builtin_amdgcn_mfma_f32_16x16x32_bf16(av[0][kk], bv[n][kk], r0[n], 0, 0, 0);
        r1[n] = __builtin_amdgcn_mfma_f32_16x16x32_bf16(av[1][kk], bv[n][kk], r1[n], 0, 0, 0);
      }
    }
    __builtin_amdgcn_s_setprio(0);
  };

  // prologue: stage t0 fully, then t1 fully; drain t0 (own) + barrier (global)
  stA(0, 0, 0); stA(0, 1, 0); stB(0, 0, 0); stB(0, 1, 0);
  stA(1, 0, 1); stA(1, 1, 1); stB(1, 0, 1); stB(1, 1, 1);
  VMCNT(8);
  BARRIER();

  bf16x8 bv[4][2], avX[2][2], avY[2][2];
  rdB(&lds[49152], bv);        // B(t0)
  rdA(&lds[0], 0, avX);        // A(t0) q0

  int aslot = 0, bslot = 0;
  for (int t = 0; t < NT; ++t) {
    const unsigned short* As = &lds[aslot * 16384];
    int a2 = aslot + 2; if (a2 >= 3) a2 -= 3;   // A slot of tile t+2
    int an = aslot + 1; if (an >= 3) an -= 3;   // A slot of tile t+1
    const unsigned short* AsN = &lds[an * 16384];
    const unsigned short* BsN = &lds[49152 + (bslot ^ 1) * 16384];
    const bool pf = (t + 2 < NT);

    // ---- ph0: read q1 ahead; stage (t+2).A0; MFMA q0 ----
    rdA(As, 1, avY);
    if (pf) stA(a2, 0, t + 2);
    BARRIER();
    mfma16(avX, bv, acc[0], acc[1]);
    BARRIER();

    // ---- ph1: read q2 ahead; stage (t+2).A1 + (t+2).B0; MFMA q1 ----
    rdA(As, 2, avX);
    if (pf) { stA(a2, 1, t + 2); stB(bslot, 0, t + 2); }
    BARRIER();
    mfma16(avY, bv, acc[2], acc[3]);
    BARRIER();

    // ---- ph2: read q3 ahead; stage (t+2).B1; MFMA q2;
    //      then PUBLISH tile t+1: own vmcnt + barrier => globally visible ----
    rdA(As, 3, avY);
    if (pf) stB(bslot, 1, t + 2);
    BARRIER();
    mfma16(avX, bv, acc[4], acc[5]);
    if (t + 1 < NT) { if (pf) { VMCNT(8); } else { VMCNT(0); } }
    BARRIER();

    // ---- ph3: MFMA q3; preload next tile's B + q0 (AFTER publish barrier) ----
    mfma16(avY, bv, acc[6], acc[7]);
    if (t + 1 < NT) {
      rdB(BsN, bv);        // WAR on bv after q3 MFMA issue: safe in-order
      rdA(AsN, 0, avX);
    }
    BARRIER();

    aslot = an; bslot ^= 1;
  }

  // epilogue: C/D layout col=lane&15, row=(lane>>4)*4+reg
  const int colg0 = bn * BN + wn * 64 + lane15;
  const int rowg0 = bm * BM + wm * 128 + (lane >> 4) * 4;
#pragma unroll
  for (int ni = 0; ni < 4; ++ni) {
    const int colg = colg0 + ni * 16;
    const float bvs = bias[colg];
#pragma unroll
    for (int mi = 0; mi < 8; ++mi) {
      const int rowg = rowg0 + mi * 16;
#pragma unroll
      for (int r = 0; r < 4; ++r)
        C[(size_t)(rowg + r) * OUT_F + colg] = acc[mi][ni][r] + bvs;
    }
  }
}

// ---------------- fallback (only if ws too small) ----------------

__global__ void fallback_kernel(const float* __restrict__ x,
                                const float* __restrict__ wmu,
                                const float* __restrict__ wrho,
                                const float* __restrict__ weps,
                                const float* __restrict__ bmu,
                                const float* __restrict__ brho,
                                const float* __restrict__ beps,
                                float* __restrict__ out) {
  int o = blockIdx.x * blockDim.x + threadIdx.x;
  int t = blockIdx.y;
  float s = 0.f;
  const float* xr = x + (size_t)t * IN_F;
  const float* wm = wmu + (size_t)o * IN_F;
  const float* wr = wrho + (size_t)o * IN_F;
  const float* we = weps + (size_t)o * IN_F;
  for (int k = 0; k < IN_F; ++k)
    s += xr[k] * fmaf(softplus_f(wr[k]), we[k], wm[k]);
  out[(size_t)t * OUT_F + o] = s + fmaf(softplus_f(brho[o]), beps[o], bmu[o]);
}

// ---------------- launch ----------------

extern "C" void kernel_launch(void* const* d_in, const int* in_sizes, int n_in,
                              void* d_out, int out_size, void* d_ws, size_t ws_size,
                              hipStream_t stream) {
  const float* x    = (const float*)d_in[0];
  const float* wmu  = (const float*)d_in[1];
  const float* wrho = (const float*)d_in[2];
  const float* bmu  = (const float*)d_in[3];
  const float* brho = (const float*)d_in[4];
  const float* weps = (const float*)d_in[5];
  const float* beps = (const float*)d_in[6];
  float* out = (float*)d_out;

  const size_t xb_off   = 0;
  const size_t wb_off   = (size_t)TOKENS * IN_F * 2;            // 64 MB
  const size_t bias_off = wb_off + (size_t)OUT_F * IN_F * 2;    // +32 MB
  const size_t needed   = bias_off + (size_t)OUT_F * 4;

  if (ws_size < needed) {
    dim3 g(OUT_F / 256, TOKENS);
    hipLaunchKernelGGL(fallback_kernel, g, dim3(256), 0, stream,
                       x, wmu, wrho, weps, bmu, brho, beps, out);
    return;
  }

  unsigned short* xb = (unsigned short*)((char*)d_ws + xb_off);
  unsigned short* wb = (unsigned short*)((char*)d_ws + wb_off);
  float* bias = (float*)((char*)d_ws + bias_off);

  hipLaunchKernelGGL(prep_kernel, dim3(2048), dim3(256), 0, stream,
                     x, wmu, wrho, weps, bmu, brho, beps, xb, wb, bias);

  hipLaunchKernelGGL(gemm_bt_kernel,
                     dim3((TOKENS / BM) * (OUT_F / BN)), dim3(THREADS), 0, stream,
                     xb, wb, bias, out);
}

// Round 7
// 310.196 us; speedup vs baseline: 1.0224x; 1.0224x over previous
//
#include <hip/hip_runtime.h>
#include <hip/hip_bf16.h>
#include <cstdint>

#define TOKENS 8192
#define IN_F   4096
#define OUT_F  4096

#define BM 256
#define BN 256
#define BK 64
#define NT (IN_F / BK)   // 64 K-tiles
#define THREADS 512

typedef __attribute__((ext_vector_type(8))) short bf16x8;
typedef __attribute__((ext_vector_type(4))) float f32x4;

#define GLOBAL_AS __attribute__((address_space(1)))
#define LDS_AS    __attribute__((address_space(3)))

#define BARRIER() do { __builtin_amdgcn_s_barrier(); asm volatile("" ::: "memory"); } while (0)
#define VMCNT(n)  do { asm volatile("s_waitcnt vmcnt(" #n ")" ::: "memory"); } while (0)

__device__ __forceinline__ unsigned short f2bf(float f) {
  union { float f; unsigned int u; } v;
  v.f = f;
  unsigned int r = 0x7FFFu + ((v.u >> 16) & 1u);
  return (unsigned short)((v.u + r) >> 16);
}

__device__ __forceinline__ float softplus_f(float x) {
  return log1pf(expf(x));
}

// ---------------- fused prep kernel ----------------

#define NW4 ((long long)OUT_F * IN_F / 4)
#define NX4 ((long long)TOKENS * IN_F / 4)
#define NB4 (OUT_F / 4)

__global__ void prep_kernel(const float* __restrict__ x,
                            const float* __restrict__ wmu,
                            const float* __restrict__ wrho,
                            const float* __restrict__ weps,
                            const float* __restrict__ bmu,
                            const float* __restrict__ brho,
                            const float* __restrict__ beps,
                            unsigned short* __restrict__ xb,
                            unsigned short* __restrict__ wb,
                            float* __restrict__ bias) {
  long long i = (long long)blockIdx.x * blockDim.x + threadIdx.x;
  long long stride = (long long)gridDim.x * blockDim.x;
  const long long total = NW4 + NX4 + NB4;
  for (; i < total; i += stride) {
    if (i < NW4) {
      float4 m = reinterpret_cast<const float4*>(wmu)[i];
      float4 r = reinterpret_cast<const float4*>(wrho)[i];
      float4 e = reinterpret_cast<const float4*>(weps)[i];
      ushort4 o;
      o.x = f2bf(fmaf(softplus_f(r.x), e.x, m.x));
      o.y = f2bf(fmaf(softplus_f(r.y), e.y, m.y));
      o.z = f2bf(fmaf(softplus_f(r.z), e.z, m.z));
      o.w = f2bf(fmaf(softplus_f(r.w), e.w, m.w));
      reinterpret_cast<ushort4*>(wb)[i] = o;
    } else if (i < NW4 + NX4) {
      long long j = i - NW4;
      float4 m = reinterpret_cast<const float4*>(x)[j];
      ushort4 o;
      o.x = f2bf(m.x); o.y = f2bf(m.y); o.z = f2bf(m.z); o.w = f2bf(m.w);
      reinterpret_cast<ushort4*>(xb)[j] = o;
    } else {
      long long j = i - NW4 - NX4;
      float4 m = reinterpret_cast<const float4*>(bmu)[j];
      float4 r = reinterpret_cast<const float4*>(brho)[j];
      float4 e = reinterpret_cast<const float4*>(beps)[j];
      float4 o;
      o.x = fmaf(softplus_f(r.x), e.x, m.x);
      o.y = fmaf(softplus_f(r.y), e.y, m.y);
      o.z = fmaf(softplus_f(r.z), e.z, m.z);
      o.w = fmaf(softplus_f(r.w), e.w, m.w);
      reinterpret_cast<float4*>(bias)[j] = o;
    }
  }
}

// ---------------- GEMM: 256x256, 4 phases/tile, ONE barrier per phase ----------------
// LDS 160 KiB: A ring 3 x 32 KiB + B ring 2 x 32 KiB. 8 waves (2M x 4N),
// per-wave out 128x64. Fragment reads run one phase ahead (avX/avY ping-pong).
// SINGLE trailing barrier per phase (r7 change): the leading barrier protected
// nothing — every cross-tile hazard is covered by a per-wave counter drain
// BEFORE a barrier that precedes the conflicting op:
//   H1 stA(slot s) at t.ph0 vs reads of s at (t-1).ph2: drained by q3-MFMA's
//      lgkm wait before (t-1).ph3's barrier.
//   H2 stB(slot) at t.ph1 vs B-reg reads at (t-1).ph3: drained before t.ph0's
//      MFMA, hence before t.ph0's trailing barrier.
//   H3 staged-data-ready: per-wave VMCNT(8) publish at ph2 + barrier (as r6).
// Removing the lockstep lets wave skew overlap ds_read/stage streams with
// other waves' MFMA clusters (m114 mechanism).
// LDS swizzle: chunk ^= (row & 7) via pre-swizzled global source (linear
// global_load_lds dest) + matching XOR on ds_read (rule 21 involution).

__global__ __launch_bounds__(THREADS, 2) void gemm_bt_kernel(
    const unsigned short* __restrict__ A,   // [TOKENS][IN_F] bf16
    const unsigned short* __restrict__ B,   // [OUT_F][IN_F] bf16
    const float* __restrict__ bias,         // [OUT_F]
    float* __restrict__ C)                  // [TOKENS][OUT_F]
{
  __shared__ unsigned short lds[5 * 16384]; // 160 KiB

  const int tid  = threadIdx.x;
  const int lane = tid & 63;
  const int wave = tid >> 6;   // 0..7
  const int wm   = wave >> 2;  // 0..1
  const int wn   = wave & 3;   // 0..3

  // XCD-aware bijective block swizzle (512 = 8 XCD chunks x 64)
  const int bid = blockIdx.x;
  const int wg  = (bid & 7) * 64 + (bid >> 3);
  const int ch  = wg >> 6;
  const int idx = wg & 63;
  const int bm  = (ch >> 1) * 8 + (idx >> 3);  // 0..31
  const int bn  = (ch & 1) * 8 + (idx & 7);    // 0..15

  const int lane15 = lane & 15;
  const int cgrp   = lane >> 4;                // 0..3
  const int rdoff0 = lane15 * 64 + ((cgrp ^ (lane & 7)) * 8);
  const int rdoff1 = lane15 * 64 + (((4 + cgrp) ^ (lane & 7)) * 8);

  // staging: per-lane pre-swizzled global source
  const int srow = lane >> 3;                  // 0..7
  const int scol = ((lane & 7) ^ srow) * 8;    // swizzled 16B chunk -> elems
  const unsigned short* Asrc = A + (size_t)(bm * BM + wave * 16 + srow) * IN_F + scol;
  const unsigned short* Bsrc = B + (size_t)(bn * BN + wave * 16 + srow) * IN_F + scol;

  f32x4 acc[8][4] = {};

  auto stA = [&](int slot, int half, int t) {
    unsigned short* dst = &lds[slot * 16384 + half * 8192 + wave * 1024];
    const unsigned short* g = Asrc + (size_t)(half * 128) * IN_F + t * BK;
    __builtin_amdgcn_global_load_lds((const GLOBAL_AS void*)g,
                                     (LDS_AS void*)dst, 16, 0, 0);
    __builtin_amdgcn_global_load_lds((const GLOBAL_AS void*)(g + (size_t)8 * IN_F),
                                     (LDS_AS void*)(dst + 512), 16, 0, 0);
  };
  auto stB = [&](int slot, int half, int t) {
    unsigned short* dst = &lds[49152 + slot * 16384 + half * 8192 + wave * 1024];
    const unsigned short* g = Bsrc + (size_t)(half * 128) * IN_F + t * BK;
    __builtin_amdgcn_global_load_lds((const GLOBAL_AS void*)g,
                                     (LDS_AS void*)dst, 16, 0, 0);
    __builtin_amdgcn_global_load_lds((const GLOBAL_AS void*)(g + (size_t)8 * IN_F),
                                     (LDS_AS void*)(dst + 512), 16, 0, 0);
  };

  auto rdA = [&](const unsigned short* Ar, int q, bf16x8 (&av)[2][2]) {
#pragma unroll
    for (int f = 0; f < 2; ++f) {
      const unsigned short* p = Ar + (wm * 128 + q * 32 + f * 16) * 64;
      av[f][0] = *reinterpret_cast<const bf16x8*>(p + rdoff0);
      av[f][1] = *reinterpret_cast<const bf16x8*>(p + rdoff1);
    }
  };
  auto rdB = [&](const unsigned short* Br, bf16x8 (&bv)[4][2]) {
#pragma unroll
    for (int n = 0; n < 4; ++n) {
      const unsigned short* p = Br + (wn * 64 + n * 16) * 64;
      bv[n][0] = *reinterpret_cast<const bf16x8*>(p + rdoff0);
      bv[n][1] = *reinterpret_cast<const bf16x8*>(p + rdoff1);
    }
  };
  auto mfma16 = [&](bf16x8 (&av)[2][2], bf16x8 (&bv)[4][2], f32x4* r0, f32x4* r1) {
    __builtin_amdgcn_s_setprio(1);
#pragma unroll
    for (int kk = 0; kk < 2; ++kk) {
#pragma unroll
      for (int n = 0; n < 4; ++n) {
        r0[n] = __builtin_amdgcn_mfma_f32_16x16x32_bf16(av[0][kk], bv[n][kk], r0[n], 0, 0, 0);
        r1[n] = __builtin_amdgcn_mfma_f32_16x16x32_bf16(av[1][kk], bv[n][kk], r1[n], 0, 0, 0);
      }
    }
    __builtin_amdgcn_s_setprio(0);
  };

  // prologue: stage t0 fully, then t1 fully; drain t0 (own) + barrier (global)
  stA(0, 0, 0); stA(0, 1, 0); stB(0, 0, 0); stB(0, 1, 0);
  stA(1, 0, 1); stA(1, 1, 1); stB(1, 0, 1); stB(1, 1, 1);
  VMCNT(8);
  BARRIER();

  bf16x8 bv[4][2], avX[2][2], avY[2][2];
  rdB(&lds[49152], bv);        // B(t0)
  rdA(&lds[0], 0, avX);        // A(t0) q0

  int aslot = 0, bslot = 0;
  for (int t = 0; t < NT; ++t) {
    const unsigned short* As = &lds[aslot * 16384];
    int a2 = aslot + 2; if (a2 >= 3) a2 -= 3;   // A slot of tile t+2
    int an = aslot + 1; if (an >= 3) an -= 3;   // A slot of tile t+1
    const unsigned short* AsN = &lds[an * 16384];
    const unsigned short* BsN = &lds[49152 + (bslot ^ 1) * 16384];
    const bool pf = (t + 2 < NT);

    // ---- ph0: read q1 ahead; stage (t+2).A0; MFMA q0 ----
    rdA(As, 1, avY);
    if (pf) stA(a2, 0, t + 2);
    mfma16(avX, bv, acc[0], acc[1]);
    BARRIER();

    // ---- ph1: read q2 ahead; stage (t+2).A1 + (t+2).B0; MFMA q1 ----
    rdA(As, 2, avX);
    if (pf) { stA(a2, 1, t + 2); stB(bslot, 0, t + 2); }
    mfma16(avY, bv, acc[2], acc[3]);
    BARRIER();

    // ---- ph2: read q3 ahead; stage (t+2).B1; MFMA q2;
    //      publish tile t+1: own vmcnt + barrier => globally visible ----
    rdA(As, 3, avY);
    if (pf) stB(bslot, 1, t + 2);
    mfma16(avX, bv, acc[4], acc[5]);
    if (t + 1 < NT) { if (pf) { VMCNT(8); } else { VMCNT(0); } }
    BARRIER();

    // ---- ph3: MFMA q3; preload next tile's B + q0 (AFTER publish barrier) ----
    mfma16(avY, bv, acc[6], acc[7]);
    if (t + 1 < NT) {
      rdB(BsN, bv);        // WAR on bv after q3 MFMA: safe in program order
      rdA(AsN, 0, avX);
    }
    BARRIER();

    aslot = an; bslot ^= 1;
  }

  // epilogue: C/D layout col=lane&15, row=(lane>>4)*4+reg
  const int colg0 = bn * BN + wn * 64 + lane15;
  const int rowg0 = bm * BM + wm * 128 + (lane >> 4) * 4;
#pragma unroll
  for (int ni = 0; ni < 4; ++ni) {
    const int colg = colg0 + ni * 16;
    const float bvs = bias[colg];
#pragma unroll
    for (int mi = 0; mi < 8; ++mi) {
      const int rowg = rowg0 + mi * 16;
#pragma unroll
      for (int r = 0; r < 4; ++r)
        C[(size_t)(rowg + r) * OUT_F + colg] = acc[mi][ni][r] + bvs;
    }
  }
}

// ---------------- fallback (only if ws too small) ----------------

__global__ void fallback_kernel(const float* __restrict__ x,
                                const float* __restrict__ wmu,
                                const float* __restrict__ wrho,
                                const float* __restrict__ weps,
                                const float* __restrict__ bmu,
                                const float* __restrict__ brho,
                                const float* __restrict__ beps,
                                float* __restrict__ out) {
  int o = blockIdx.x * blockDim.x + threadIdx.x;
  int t = blockIdx.y;
  float s = 0.f;
  const float* xr = x + (size_t)t * IN_F;
  const float* wm = wmu + (size_t)o * IN_F;
  const float* wr = wrho + (size_t)o * IN_F;
  const float* we = weps + (size_t)o * IN_F;
  for (int k = 0; k < IN_F; ++k)
    s += xr[k] * fmaf(softplus_f(wr[k]), we[k], wm[k]);
  out[(size_t)t * OUT_F + o] = s + fmaf(softplus_f(brho[o]), beps[o], bmu[o]);
}

// ---------------- launch ----------------

extern "C" void kernel_launch(void* const* d_in, const int* in_sizes, int n_in,
                              void* d_out, int out_size, void* d_ws, size_t ws_size,
                              hipStream_t stream) {
  const float* x    = (const float*)d_in[0];
  const float* wmu  = (const float*)d_in[1];
  const float* wrho = (const float*)d_in[2];
  const float* bmu  = (const float*)d_in[3];
  const float* brho = (const float*)d_in[4];
  const float* weps = (const float*)d_in[5];
  const float* beps = (const float*)d_in[6];
  float* out = (float*)d_out;

  const size_t xb_off   = 0;
  const size_t wb_off   = (size_t)TOKENS * IN_F * 2;            // 64 MB
  const size_t bias_off = wb_off + (size_t)OUT_F * IN_F * 2;    // +32 MB
  const size_t needed   = bias_off + (size_t)OUT_F * 4;

  if (ws_size < needed) {
    dim3 g(OUT_F / 256, TOKENS);
    hipLaunchKernelGGL(fallback_kernel, g, dim3(256), 0, stream,
                       x, wmu, wrho, weps, bmu, brho, beps, out);
    return;
  }

  unsigned short* xb = (unsigned short*)((char*)d_ws + xb_off);
  unsigned short* wb = (unsigned short*)((char*)d_ws + wb_off);
  float* bias = (float*)((char*)d_ws + bias_off);

  hipLaunchKernelGGL(prep_kernel, dim3(2048), dim3(256), 0, stream,
                     x, wmu, wrho, weps, bmu, brho, beps, xb, wb, bias);

  hipLaunchKernelGGL(gemm_bt_kernel,
                     dim3((TOKENS / BM) * (OUT_F / BN)), dim3(THREADS), 0, stream,
                     xb, wb, bias, out);
}